// Round 1
// 139.927 us; speedup vs baseline: 1.0037x; 1.0037x over previous
//
#include <hip/hip_runtime.h>
#include <hip/hip_bf16.h>

#define B_ 8
#define T_ 2048
#define NROWS 16384

typedef __attribute__((ext_vector_type(16))) float f32x16;
typedef __attribute__((ext_vector_type(8))) short short8;
typedef __fp16 half2_t __attribute__((ext_vector_type(2)));
typedef __fp16 half8_t __attribute__((ext_vector_type(8)));

__device__ __forceinline__ unsigned int pkrtz(float a, float b) {
    half2_t h = __builtin_amdgcn_cvt_pkrtz(a, b);
    return __builtin_bit_cast(unsigned int, h);
}
// pack two fp32 into one dword of bf16 (truncate): low short = a, high = b
__device__ __forceinline__ unsigned int pkbf(float a, float b) {
    return __builtin_amdgcn_perm(__float_as_uint(b), __float_as_uint(a), 0x07060302u);
}
__device__ __forceinline__ float dot2(unsigned int a, unsigned int b, float c) {
    return __builtin_amdgcn_fdot2(__builtin_bit_cast(half2_t, a),
                                  __builtin_bit_cast(half2_t, b), c, false);
}
__device__ __forceinline__ float fast_exp2(float x) {
#if __has_builtin(__builtin_amdgcn_exp2f)
    return __builtin_amdgcn_exp2f(x);
#else
    return exp2f(x);
#endif
}
// async global->LDS, 16B per lane. LDS dest must be wave-uniform base + lane*16.
__device__ __forceinline__ void gl_lds16(const void* g, void* l) {
    __builtin_amdgcn_global_load_lds(
        (const __attribute__((address_space(1))) unsigned int*)g,
        (__attribute__((address_space(3))) unsigned int*)l, 16, 0, 0);
}

// ---------------------------------------------------------------------------
// Kernel 1: QKV projection (dot2) + cos(.+theta) + bf16 pack to [B,H,T,DK].
// (unchanged)
// ---------------------------------------------------------------------------
__global__ __launch_bounds__(512, 2) void qkv_kernel(
    const float* __restrict__ x,
    const float* __restrict__ Wq, const float* __restrict__ bq,
    const float* __restrict__ Wk, const float* __restrict__ bk,
    const float* __restrict__ Wv, const float* __restrict__ bv,
    const float* __restrict__ theta_attn,
    unsigned short* __restrict__ qb, unsigned short* __restrict__ kbuf,
    unsigned short* __restrict__ vbuf)
{
    __shared__ unsigned int xpk[32 * 66];
    __shared__ unsigned int wpk[32 * 196];
    __shared__ unsigned int outs[6144];
    const int tid = threadIdx.x;
    const int n0 = blockIdx.x * 64;

    #pragma unroll
    for (int t = 0; t < 2; t++) {
        int fi = tid + t * 512;
        float4 v = ((const float4*)(x + (size_t)n0 * 64))[fi];
        int r = fi >> 4, k0 = (fi & 15) * 4;
        xpk[(k0 >> 1) * 66 + r] = pkrtz(v.x, v.y);
        xpk[((k0 >> 1) + 1) * 66 + r] = pkrtz(v.z, v.w);
    }
    const float* Wm[3] = {Wq, Wk, Wv};
    #pragma unroll
    for (int t = 0; t < 6; t++) {
        int fi = tid + t * 512;
        int m = fi >> 10, j = (fi >> 4) & 63, k0 = (fi & 15) * 4;
        float4 v = ((const float4*)Wm[m])[fi & 1023];
        wpk[(k0 >> 1) * 196 + m * 64 + j] = pkrtz(v.x, v.y);
        wpk[((k0 >> 1) + 1) * 196 + m * 64 + j] = pkrtz(v.z, v.w);
    }
    __syncthreads();

    const int r0 = (tid & 31) * 2;
    const int c0 = (tid >> 5) * 12;
    float acc[2][12] = {};
    #pragma unroll 8
    for (int kp = 0; kp < 32; kp++) {
        uint2 a = *(const uint2*)&xpk[kp * 66 + r0];
        uint4 b0 = *(const uint4*)&wpk[kp * 196 + c0];
        uint4 b1 = *(const uint4*)&wpk[kp * 196 + c0 + 4];
        uint4 b2 = *(const uint4*)&wpk[kp * 196 + c0 + 8];
        unsigned int bb[12] = {b0.x, b0.y, b0.z, b0.w,
                               b1.x, b1.y, b1.z, b1.w,
                               b2.x, b2.y, b2.z, b2.w};
        #pragma unroll
        for (int j = 0; j < 12; j++) {
            acc[0][j] = dot2(a.x, bb[j], acc[0][j]);
            acc[1][j] = dot2(a.y, bb[j], acc[1][j]);
        }
    }

    {
        const float th = *theta_attn;
        const float QS = 0.51006980f;
        const float* biasp[3] = {bq, bk, bv};
        float bcol[12];
        #pragma unroll
        for (int j = 0; j < 12; j++) {
            int c = c0 + j;
            bcol[j] = biasp[c >> 6][c & 63];
        }
        #pragma unroll
        for (int i = 0; i < 2; i++) {
            float vals[12];
            #pragma unroll
            for (int j = 0; j < 12; j++) {
                float v = __cosf(acc[i][j] + bcol[j] + th);
                vals[j] = ((c0 + j) >> 6) == 0 ? v * QS : v;
            }
            int row = r0 + i;
            #pragma unroll
            for (int t = 0; t < 6; t++) {
                int c = c0 + 2 * t;
                outs[(c >> 3) * 256 + row * 4 + ((c & 7) >> 1)] = pkbf(vals[2*t], vals[2*t+1]);
            }
        }
    }
    __syncthreads();

    unsigned short* outp3[3] = {qb, kbuf, vbuf};
    #pragma unroll
    for (int t = 0; t < 3; t++) {
        int fi = tid + t * 512;
        int bh = fi >> 6, r2 = fi & 63;
        int m = bh >> 3, hI = bh & 7;
        uint4 v = *(const uint4*)&outs[4 * fi];
        int n = n0 + r2;
        unsigned short* dst = outp3[m] +
            ((size_t)((n >> 11) * 8 + hI) * 2048 + (n & 2047)) * 8;
        *(uint4*)dst = v;
    }
}

// ---------------------------------------------------------------------------
// Kernel 2: flash attention.
// Round-8 changes:
//  - K staged via async global_load_lds dwordx4 (dest is wave-uniform base +
//    lane*16 by construction: s = wave*64+lane+it*256, linear row-major).
//  - V staged via register prefetch (vr): half-1's loads are issued right
//    after half-0's pre-compute barrier, so their latency hides under the
//    32-iteration exp2/MFMA loop (T14 async-STAGE split).
//  - Output written as fp16 pairs (uint2/lane, coalesced) -- the tail
//    consumed it via pkrtz anyway; saves the fp32 round trip (5 MB HBM).
// ---------------------------------------------------------------------------
__global__ __launch_bounds__(256, 4) void attn_kernel(
    const unsigned short* __restrict__ qb,
    const unsigned short* __restrict__ kbuf,
    const unsigned short* __restrict__ vbuf,
    unsigned int* __restrict__ attn)
{
    __shared__ __align__(16) unsigned short Ks[1024 * 8];
    __shared__ __align__(16) unsigned short Vt[9 * 1032];
    const int tid = threadIdx.x;
    const int head = blockIdx.x >> 4;
    const int qblk = blockIdx.x & 15;
    const size_t hoff = (size_t)head * T_ * 8;
    const int wave = tid >> 6, lane = tid & 63;
    const int col = lane & 31, h = lane >> 5;
    const int q0 = qblk * 128 + wave * 32;

    const short8 z8 = {0, 0, 0, 0, 0, 0, 0, 0};
    short8 bqf = z8;
    if (h == 0) bqf = *(const short8*)(qb + hoff + (size_t)(q0 + col) * 8);

    if (tid < 128)
        ((uint4*)(Vt + 8 * 1032))[tid] =
            make_uint4(0x3f803f80u, 0x3f803f80u, 0x3f803f80u, 0x3f803f80u);

    // prologue: issue K half-0 -> LDS (async, no VGPRs), V half-0 -> regs
    #pragma unroll
    for (int it = 0; it < 4; it++) {
        int s = tid + it * 256;
        gl_lds16(kbuf + hoff + (size_t)s * 8, &Ks[s * 8]);
    }
    uint4 vr[4];
    {
        const uint4* vg = (const uint4*)(vbuf + hoff);
        #pragma unroll
        for (int it = 0; it < 4; it++) vr[it] = vg[tid + it * 256];
    }

    f32x16 oacc = {0.f,0.f,0.f,0.f,0.f,0.f,0.f,0.f,0.f,0.f,0.f,0.f,0.f,0.f,0.f,0.f};
    const f32x16 z16 = {0.f,0.f,0.f,0.f,0.f,0.f,0.f,0.f,0.f,0.f,0.f,0.f,0.f,0.f,0.f,0.f};
    const unsigned short* vbase = &Vt[(col < 9 ? col : 8) * 1032 + 8 * h];
    short8 ak = z8;

    for (int half = 0; half < 2; half++) {
        __syncthreads();                    // prev compute done reading Ks/Vt
        if (half == 1) {
            #pragma unroll
            for (int it = 0; it < 4; it++) {
                int s = tid + it * 256;
                gl_lds16(kbuf + hoff + 8192 + (size_t)s * 8, &Ks[s * 8]);
            }
        }
        #pragma unroll
        for (int it = 0; it < 4; it++) {
            int s = tid + it * 256;
            union { uint4 u; unsigned short us[8]; } cv;
            cv.u = vr[it];
            int sp = (s & ~12) | ((s & 4) << 1) | ((s & 8) >> 1);
            #pragma unroll
            for (int d = 0; d < 8; d++) Vt[d * 1032 + sp] = cv.us[d];
        }
        __syncthreads();                    // drains K gl_lds (vmcnt 0) + Vt writes
        if (half == 0) {
            const uint4* vg = (const uint4*)(vbuf + hoff + 8192);
            #pragma unroll
            for (int it = 0; it < 4; it++) vr[it] = vg[tid + it * 256];
        }

        for (int s0 = 0; s0 < 1024; s0 += 32) {
            if (h == 0) ak = *(const short8*)&Ks[(s0 + col) * 8];
            f32x16 S = __builtin_amdgcn_mfma_f32_32x32x16_bf16(ak, bqf, z16, 0, 0, 0);
            #pragma unroll
            for (int g = 0; g < 2; g++) {
                const int o = g * 8;
                union { unsigned int u[4]; short8 s; } bp;
                bp.u[0] = pkbf(fast_exp2(S[o+0]), fast_exp2(S[o+1]));
                bp.u[1] = pkbf(fast_exp2(S[o+2]), fast_exp2(S[o+3]));
                bp.u[2] = pkbf(fast_exp2(S[o+4]), fast_exp2(S[o+5]));
                bp.u[3] = pkbf(fast_exp2(S[o+6]), fast_exp2(S[o+7]));
                short8 av = *(const short8*)&vbase[s0 + g * 16];
                oacc = __builtin_amdgcn_mfma_f32_32x32x16_bf16(av, bp.s, oacc, 0, 0, 0);
            }
        }
    }

    float tot = oacc[4];
    tot += __shfl_xor(tot, 32);
    const float inv = 1.0f / tot;
    const int bI = head >> 3, hI = head & 7;
    const int q = q0 + col;
    uint2 o2;
    o2.x = pkrtz(oacc[0] * inv, oacc[1] * inv);
    o2.y = pkrtz(oacc[2] * inv, oacc[3] * inv);
    *(uint2*)(attn + ((size_t)(bI * 2048 + q)) * 32 + hI * 4 + 2 * h) = o2;
}

// ---------------------------------------------------------------------------
// Kernel 3 (fused tail, MFMA-based): y=At@Wo^T+bo; x1=LN(x+y);
// qout=cos(x1)cos(thf); h=relu(qout@W1^T+b1); f=h@W2^T+b2; out=LN(x1+f).
// Round-8 change: attn arrives as fp16 pairs -> At stage is a plain uint2
// copy (no float4 load + pkrtz). Everything else unchanged.
// ---------------------------------------------------------------------------
__global__ __launch_bounds__(512, 4) void tail_kernel(
    const unsigned int* __restrict__ attn, const float* __restrict__ x,
    const float* __restrict__ Wo, const float* __restrict__ bo,
    const float* __restrict__ g1, const float* __restrict__ be1,
    const float* __restrict__ theta_ffn,
    const float* __restrict__ W1, const float* __restrict__ b1,
    const float* __restrict__ W2, const float* __restrict__ b2,
    const float* __restrict__ g2, const float* __restrict__ be2,
    float* __restrict__ outp)
{
    __shared__ __align__(16) unsigned int smem[15744];
    const int tid = threadIdx.x;
    const int lane = tid & 63;
    const int wave = tid >> 6;
    const int h = lane >> 5;
    const int n0 = blockIdx.x * 32;
    const int mrow = tid >> 4;             // epilogue row 0..31
    const int c0 = (tid & 15) * 4;         // epilogue cols

    unsigned int* const W1p = smem;
    unsigned int* const W2p = smem;
    unsigned int* const Atp = smem + 9216;
    unsigned int* const qoutp = smem + 9216;
    unsigned int* const Wop = smem + 10368;
    unsigned int* const hrowp = smem + 10368;
    float* const Yf = (float*)(smem + 12672);
    float* const Y2a = (float*)(smem + 14592);
    float* const Y2b = (float*)(smem + 8448);

    const f32x16 z16 = {0.f,0.f,0.f,0.f,0.f,0.f,0.f,0.f,0.f,0.f,0.f,0.f,0.f,0.f,0.f,0.f};

    // ---- early global issues ----
    uint2 at2 = ((const uint2*)attn)[(size_t)n0 * 16 + tid];
    float4 wo0 = ((const float4*)Wo)[tid];
    float4 wo1 = ((const float4*)Wo)[tid + 512];
    float4 xv = *(const float4*)(x + (size_t)(n0 + mrow) * 64 + c0);
    float4 w1r[8];
    #pragma unroll
    for (int t = 0; t < 8; t++) w1r[t] = ((const float4*)W1)[tid + t * 512];

    // ---- stage At [32][36] + Wo [64][36] row-major fp16 pairs ----
    {
        int r = tid >> 4, k0 = (tid & 15) * 4;
        *(uint2*)&Atp[r * 36 + (k0 >> 1)] = at2;
        uint2 wa = make_uint2(pkrtz(wo0.x, wo0.y), pkrtz(wo0.z, wo0.w));
        *(uint2*)&Wop[r * 36 + (k0 >> 1)] = wa;
        int fi = tid + 512;
        int e1 = fi >> 4, k1 = (fi & 15) * 4;
        uint2 wb = make_uint2(pkrtz(wo1.x, wo1.y), pkrtz(wo1.z, wo1.w));
        *(uint2*)&Wop[e1 * 36 + (k1 >> 1)] = wb;
    }
    __syncthreads();                        // B1: At, Wo ready

    // ---- W1 regs -> W1p [256][36] (all threads) ----
    #pragma unroll
    for (int t = 0; t < 8; t++) {
        int fi = tid + t * 512;
        int f = fi >> 4, k0 = (fi & 15) * 4;
        uint2 w2 = make_uint2(pkrtz(w1r[t].x, w1r[t].y), pkrtz(w1r[t].z, w1r[t].w));
        *(uint2*)&W1p[f * 36 + (k0 >> 1)] = w2;
    }

    // ---- G1: y = At @ Wo^T + bo  (waves 0-1, one 32-col tile each) ----
    if (wave < 2) {
        const int colo = wave * 32 + (lane & 31);
        f32x16 acc = z16;
        #pragma unroll
        for (int kk = 0; kk < 4; kk++) {
            half8_t a = __builtin_bit_cast(half8_t,
                *(const uint4*)&Atp[(lane & 31) * 36 + kk * 8 + h * 4]);
            half8_t b = __builtin_bit_cast(half8_t,
                *(const uint4*)&Wop[colo * 36 + kk * 8 + h * 4]);
            acc = __builtin_amdgcn_mfma_f32_32x32x16_f16(a, b, acc, 0, 0, 0);
        }
        float bov = bo[colo];
        #pragma unroll
        for (int reg = 0; reg < 16; reg++) {
            int rr = (reg & 3) + 8 * (reg >> 2) + 4 * h;
            Yf[rr * 68 + colo] = acc[reg] + bov;
        }
    }
    __syncthreads();                        // B2: Y + W1p ready

    // ---- ep1: x1 = LN(x+y) (regs); qout = cos(x1)*cos(thf) -> qoutp ----
    float x1v[4];
    {
        float4 yv = *(const float4*)&Yf[mrow * 68 + c0];
        float vv[4] = {xv.x + yv.x, xv.y + yv.y, xv.z + yv.z, xv.w + yv.w};
        float s1 = vv[0] + vv[1] + vv[2] + vv[3];
        float s2 = vv[0]*vv[0] + vv[1]*vv[1] + vv[2]*vv[2] + vv[3]*vv[3];
        #pragma unroll
        for (int m = 1; m <= 8; m <<= 1) {
            s1 += __shfl_xor(s1, m);
            s2 += __shfl_xor(s2, m);
        }
        float mean = s1 * 0.015625f;
        float rstd = rsqrtf(s2 * 0.015625f - mean * mean + 1e-5f);
        float4 g14 = *(const float4*)&g1[c0];
        float4 be14 = *(const float4*)&be1[c0];
        float gg[4] = {g14.x, g14.y, g14.z, g14.w};
        float eb[4] = {be14.x, be14.y, be14.z, be14.w};
        float cth = __cosf(*theta_ffn);
        float qv[4];
        #pragma unroll
        for (int j = 0; j < 4; j++) {
            x1v[j] = (vv[j] - mean) * rstd * gg[j] + eb[j];
            qv[j] = __cosf(x1v[j]) * cth;
        }
        uint2 q2 = make_uint2(pkrtz(qv[0], qv[1]), pkrtz(qv[2], qv[3]));
        *(uint2*)&qoutp[mrow * 36 + (c0 >> 1)] = q2;
    }
    __syncthreads();                        // B3: qout ready

    // ---- W2 prefetch (in flight across G2) ----
    float4 w2r[8];
    #pragma unroll
    for (int t = 0; t < 8; t++) w2r[t] = ((const float4*)W2)[tid + t * 512];

    // ---- G2: h^T = W1 @ qout^T (C^T form), relu+bias, -> hrowp row-major ----
    {
        const int fl = lane & 31;
        f32x16 acc = z16;
        #pragma unroll
        for (int kk = 0; kk < 4; kk++) {
            half8_t a = __builtin_bit_cast(half8_t,
                *(const uint4*)&W1p[(wave * 32 + fl) * 36 + kk * 8 + h * 4]);
            half8_t b = __builtin_bit_cast(half8_t,
                *(const uint4*)&qoutp[fl * 36 + kk * 8 + h * 4]);
            acc = __builtin_amdgcn_mfma_f32_32x32x16_f16(a, b, acc, 0, 0, 0);
        }
        const int row = lane & 31;          // x-row = C col
        #pragma unroll
        for (int q = 0; q < 4; q++) {       // regs 4q..4q+3 = f 8q+4h+0..3 (+32*wave)
            int fb = wave * 32 + 8 * q + 4 * h;
            float4 b1v = *(const float4*)&b1[fb];
            float h0 = fmaxf(acc[4*q+0] + b1v.x, 0.f);
            float h1 = fmaxf(acc[4*q+1] + b1v.y, 0.f);
            float h2 = fmaxf(acc[4*q+2] + b1v.z, 0.f);
            float h3 = fmaxf(acc[4*q+3] + b1v.w, 0.f);
            uint2 hp = make_uint2(pkrtz(h0, h1), pkrtz(h2, h3));
            *(uint2*)&hrowp[row * 132 + (fb >> 1)] = hp;
        }
    }
    __syncthreads();                        // B4: hrow ready, W1 dead

    // ---- W2 regs -> W2p [64][132] row-major ----
    #pragma unroll
    for (int t = 0; t < 8; t++) {
        int fi = tid + t * 512;
        int e = fi >> 6, k0 = (fi & 63) * 4;
        uint2 w2 = make_uint2(pkrtz(w2r[t].x, w2r[t].y), pkrtz(w2r[t].z, w2r[t].w));
        *(uint2*)&W2p[e * 132 + (k0 >> 1)] = w2;
    }
    __syncthreads();                        // B5: W2p ready

    // ---- G3: f = h @ W2^T + b2  (waves 0-1, one 32-col tile each) ----
    if (wave < 2) {
        const int colo = wave * 32 + (lane & 31);
        f32x16 acc = z16;
        #pragma unroll
        for (int kk = 0; kk < 16; kk++) {
            half8_t a = __builtin_bit_cast(half8_t,
                *(const uint4*)&hrowp[(lane & 31) * 132 + kk * 8 + h * 4]);
            half8_t b = __builtin_bit_cast(half8_t,
                *(const uint4*)&W2p[colo * 132 + kk * 8 + h * 4]);
            acc = __builtin_amdgcn_mfma_f32_32x32x16_f16(a, b, acc, 0, 0, 0);
        }
        float b2v = b2[colo];
        float* Ydst = wave ? Y2b : Y2a;
        const int cl = lane & 31;
        #pragma unroll
        for (int reg = 0; reg < 16; reg++) {
            int rr = (reg & 3) + 8 * (reg >> 2) + 4 * h;
            Ydst[rr * 36 + cl] = acc[reg] + b2v;
        }
    }
    __syncthreads();                        // B6: Y2 ready

    // ---- ep3: out = LN(x1 + f) * g2 + be2 ----
    {
        float4 fv = (c0 < 32) ? *(const float4*)&Y2a[mrow * 36 + c0]
                              : *(const float4*)&Y2b[mrow * 36 + (c0 - 32)];
        float vv[4] = {x1v[0] + fv.x, x1v[1] + fv.y, x1v[2] + fv.z, x1v[3] + fv.w};
        float s1 = vv[0] + vv[1] + vv[2] + vv[3];
        float s2 = vv[0]*vv[0] + vv[1]*vv[1] + vv[2]*vv[2] + vv[3]*vv[3];
        #pragma unroll
        for (int m = 1; m <= 8; m <<= 1) {
            s1 += __shfl_xor(s1, m);
            s2 += __shfl_xor(s2, m);
        }
        float mean = s1 * 0.015625f;
        float rstd = rsqrtf(s2 * 0.015625f - mean * mean + 1e-5f);
        float4 g24 = *(const float4*)&g2[c0];
        float4 be24 = *(const float4*)&be2[c0];
        float4 o;
        o.x = (vv[0] - mean) * rstd * g24.x + be24.x;
        o.y = (vv[1] - mean) * rstd * g24.y + be24.y;
        o.z = (vv[2] - mean) * rstd * g24.z + be24.z;
        o.w = (vv[3] - mean) * rstd * g24.w + be24.w;
        *(float4*)(outp + (size_t)(n0 + mrow) * 64 + c0) = o;
    }
}

// ---------------------------------------------------------------------------
extern "C" void kernel_launch(void* const* d_in, const int* in_sizes, int n_in,
                              void* d_out, int out_size, void* d_ws, size_t ws_size,
                              hipStream_t stream)
{
    const float* x   = (const float*)d_in[0];
    const float* Wq  = (const float*)d_in[1];
    const float* bq  = (const float*)d_in[2];
    const float* Wk  = (const float*)d_in[3];
    const float* bk  = (const float*)d_in[4];
    const float* Wv  = (const float*)d_in[5];
    const float* bv  = (const float*)d_in[6];
    const float* Wo  = (const float*)d_in[7];
    const float* bo  = (const float*)d_in[8];
    const float* tha = (const float*)d_in[9];
    const float* thf = (const float*)d_in[10];
    const float* W1  = (const float*)d_in[11];
    const float* b1  = (const float*)d_in[12];
    const float* W2  = (const float*)d_in[13];
    const float* b2  = (const float*)d_in[14];
    const float* g1  = (const float*)d_in[15];
    const float* be1 = (const float*)d_in[16];
    const float* g2  = (const float*)d_in[17];
    const float* be2 = (const float*)d_in[18];

    // workspace: qb(2M) kb(2M) vb(2M) attn-fp16(1M)
    char* wsb = (char*)d_ws;
    unsigned short* qbp = (unsigned short*)(wsb);
    unsigned short* kbp = (unsigned short*)(wsb + (2u << 20));
    unsigned short* vbp = (unsigned short*)(wsb + (4u << 20));
    unsigned int* attn = (unsigned int*)(wsb + (6u << 20));

    qkv_kernel<<<256, 512, 0, stream>>>(x, Wq, bq, Wk, bk, Wv, bv, tha, qbp, kbp, vbp);
    attn_kernel<<<1024, 256, 0, stream>>>(qbp, kbp, vbp, attn);
    tail_kernel<<<512, 512, 0, stream>>>(attn, x, Wo, bo, g1, be1, thf,
                                         W1, b1, W2, b2, g2, be2, (float*)d_out);
}